// Round 1
// baseline (1954.683 us; speedup 1.0000x reference)
//
#include <hip/hip_runtime.h>
#include <math.h>

#define NN 50000
#define NE 1600000
#define FIN 128
#define EH 20
#define DH 64

// ---------------- kernels ----------------

// init deg=1 (self loop) and detect edge_index element width (int64 vs int32)
__global__ void k_init(float* deg, int* flag, const void* ei) {
    int i = blockIdx.x * blockDim.x + threadIdx.x;
    if (i < NN) deg[i] = 1.0f;
    if (blockIdx.x == 0 && threadIdx.x == 0) {
        const int* w = (const int*)ei;
        int all0 = 1;
        for (int j = 1; j < 128; j += 2) all0 &= (w[j] == 0);
        *flag = all0;  // 1 => int64 layout (high words zero), 0 => int32
    }
}

// convert edge_index to int32 r/c arrays and accumulate in-degree of col
__global__ void k_cvt_deg(const void* ei, const int* flag, int* r32, int* c32, float* deg) {
    int e = blockIdx.x * blockDim.x + threadIdx.x;
    if (e >= NE) return;
    int r, c;
    if (*flag) {
        const long long* p = (const long long*)ei;
        r = (int)p[e];
        c = (int)p[NE + e];
    } else {
        const int* p = (const int*)ei;
        r = p[e];
        c = p[NE + e];
    }
    r32[e] = r;
    c32[e] = c;
    atomicAdd(&deg[c], 1.0f);
}

__global__ void k_dinv(const float* deg, float* dinv) {
    int i = blockIdx.x * blockDim.x + threadIdx.x;
    if (i < NN) dinv[i] = rsqrtf(deg[i]);
}

// h[n,k] = dot(x[n,:], W[:,k]) ; 32 threads per node, k = lane (k<20 active)
__global__ void k_xw(const float* __restrict__ x, const float* __restrict__ W,
                     float* __restrict__ h) {
    int t = blockIdx.x * blockDim.x + threadIdx.x;
    int n = t >> 5;
    int k = t & 31;
    if (n >= NN || k >= EH) return;
    const float* xr = x + (size_t)n * FIN;
    float acc = 0.f;
#pragma unroll 8
    for (int j = 0; j < FIN; ++j) acc = fmaf(xr[j], W[j * EH + k], acc);
    h[n * EH + k] = acc;
}

// agg init = self-loop contribution dinv[n]^2 * h[n,k]
__global__ void k_selfinit(const float* __restrict__ dinv, const float* __restrict__ h,
                           float* __restrict__ agg) {
    int i = blockIdx.x * blockDim.x + threadIdx.x;
    if (i >= NN * EH) return;
    int n = i / EH;
    float d = dinv[n];
    agg[i] = d * d * h[i];
}

// scatter: agg[c,:] += dinv[r]*dinv[c]*h[r,:]
__global__ void k_scatter(const int* __restrict__ r32, const int* __restrict__ c32,
                          const float* __restrict__ dinv, const float* __restrict__ h,
                          float* __restrict__ agg) {
    int e = blockIdx.x * blockDim.x + threadIdx.x;
    if (e >= NE) return;
    int r = r32[e], c = c32[e];
    float nrm = dinv[r] * dinv[c];
    const float4* h4 = (const float4*)(h + (size_t)r * EH);
    float4 v0 = h4[0], v1 = h4[1], v2 = h4[2], v3 = h4[3], v4 = h4[4];
    float* ac = agg + (size_t)c * EH;
    atomicAdd(&ac[0],  nrm * v0.x); atomicAdd(&ac[1],  nrm * v0.y);
    atomicAdd(&ac[2],  nrm * v0.z); atomicAdd(&ac[3],  nrm * v0.w);
    atomicAdd(&ac[4],  nrm * v1.x); atomicAdd(&ac[5],  nrm * v1.y);
    atomicAdd(&ac[6],  nrm * v1.z); atomicAdd(&ac[7],  nrm * v1.w);
    atomicAdd(&ac[8],  nrm * v2.x); atomicAdd(&ac[9],  nrm * v2.y);
    atomicAdd(&ac[10], nrm * v2.z); atomicAdd(&ac[11], nrm * v2.w);
    atomicAdd(&ac[12], nrm * v3.x); atomicAdd(&ac[13], nrm * v3.y);
    atomicAdd(&ac[14], nrm * v3.z); atomicAdd(&ac[15], nrm * v3.w);
    atomicAdd(&ac[16], nrm * v4.x); atomicAdd(&ac[17], nrm * v4.y);
    atomicAdd(&ac[18], nrm * v4.z); atomicAdd(&ac[19], nrm * v4.w);
}

// h1 = relu(agg + b) in place
__global__ void k_biasrelu(float* __restrict__ h1, const float* __restrict__ b) {
    int i = blockIdx.x * blockDim.x + threadIdx.x;
    if (i >= NN * EH) return;
    int k = i % EH;
    h1[i] = fmaxf(h1[i] + b[k], 0.f);
}

// A[n,j] = h1[n,:] @ W1[0:20, j];  B[n,j] = h1[n,:] @ W1[20:40, j]
__global__ void k_ab(const float* __restrict__ h1, const float* __restrict__ W1,
                     float* __restrict__ A, float* __restrict__ B) {
    int t = blockIdx.x * blockDim.x + threadIdx.x;
    int n = t >> 6;
    int j = t & 63;
    if (n >= NN) return;
    const float* hr = h1 + (size_t)n * EH;
    float a = 0.f, b = 0.f;
#pragma unroll
    for (int k = 0; k < EH; ++k) {
        float hv = hr[k];
        a = fmaf(hv, W1[k * DH + j], a);
        b = fmaf(hv, W1[(EH + k) * DH + j], b);
    }
    A[(size_t)n * DH + j] = a;
    B[(size_t)n * DH + j] = b;
}

// cn[j] = h1[node_id,:] @ W1[40:60, j] + b1[j]
__global__ void k_cn(const float* __restrict__ h1, const float* __restrict__ W1,
                     const float* __restrict__ b1, const void* nid_p,
                     float* __restrict__ cn) {
    int j = threadIdx.x;  // 64 threads
    int nid = *(const int*)nid_p;  // low 32 bits valid for int32 or int64
    const float* hr = h1 + (size_t)nid * EH;
    float acc = b1[j];
#pragma unroll
    for (int k = 0; k < EH; ++k) acc = fmaf(hr[k], W1[(2 * EH + k) * DH + j], acc);
    cn[j] = acc;
}

// per-edge: out = sigmoid(logit(e) + relu(A[r]+B[c]+cn)@W2 + b2); 16 lanes/edge
__global__ void k_edge(const int* __restrict__ r32, const int* __restrict__ c32,
                       const float* __restrict__ A, const float* __restrict__ B,
                       const float* __restrict__ cn, const float* __restrict__ W2,
                       const float* __restrict__ b2, const float* __restrict__ eps,
                       float* __restrict__ out) {
    int t = blockIdx.x * blockDim.x + threadIdx.x;
    int e = t >> 4;
    if (e >= NE) return;
    int lane = t & 15;
    int r = r32[e], c = c32[e];
    float4 a  = *(const float4*)(A  + (size_t)r * DH + lane * 4);
    float4 bb = *(const float4*)(B  + (size_t)c * DH + lane * 4);
    float4 cc = *(const float4*)(cn + lane * 4);
    float4 w  = *(const float4*)(W2 + lane * 4);
    float p = fmaxf(a.x + bb.x + cc.x, 0.f) * w.x
            + fmaxf(a.y + bb.y + cc.y, 0.f) * w.y
            + fmaxf(a.z + bb.z + cc.z, 0.f) * w.z
            + fmaxf(a.w + bb.w + cc.w, 0.f) * w.w;
    p += __shfl_xor(p, 1);
    p += __shfl_xor(p, 2);
    p += __shfl_xor(p, 4);
    p += __shfl_xor(p, 8);
    if (lane == 0) {
        float ep = eps[e];
        // e = (bias-(1-bias))*eps + (1-bias), bias=1e-4
        float ee = fmaf(-0.9998f, ep, 0.9999f);
        float gate = logf(ee) - log1pf(-ee) + p + b2[0];
        out[e] = 1.0f / (1.0f + expf(-gate));
    }
}

// ---------------- launch ----------------

extern "C" void kernel_launch(void* const* d_in, const int* in_sizes, int n_in,
                              void* d_out, int out_size, void* d_ws, size_t ws_size,
                              hipStream_t stream) {
    const float* x   = (const float*)d_in[0];
    const void*  ei  = d_in[1];
    const void*  nid = d_in[2];
    const float* eps = (const float*)d_in[3];
    const float* Wg  = (const float*)d_in[4];
    const float* bg  = (const float*)d_in[5];
    const float* W1  = (const float*)d_in[6];
    const float* b1  = (const float*)d_in[7];
    const float* W2  = (const float*)d_in[8];
    const float* b2  = (const float*)d_in[9];
    float* out = (float*)d_out;

    float* ws = (float*)d_ws;
    float* deg  = ws + 0;
    float* dinv = ws + 50176;
    int*   flag = (int*)(ws + 100352);
    float* cn   = ws + 100608;
    float* h    = ws + 100864;
    float* h1   = ws + 1100864;
    float* A    = ws + 2100864;
    float* B    = ws + 5300864;
    int*   r32  = (int*)(ws + 8500864);
    int*   c32  = (int*)(ws + 10100864);

    dim3 blk(256);
    k_init<<<(NN + 255) / 256, blk, 0, stream>>>(deg, flag, ei);
    k_cvt_deg<<<(NE + 255) / 256, blk, 0, stream>>>(ei, flag, r32, c32, deg);
    k_dinv<<<(NN + 255) / 256, blk, 0, stream>>>(deg, dinv);
    k_xw<<<(NN * 32 + 255) / 256, blk, 0, stream>>>(x, Wg, h);
    k_selfinit<<<(NN * EH + 255) / 256, blk, 0, stream>>>(dinv, h, h1);
    k_scatter<<<(NE + 255) / 256, blk, 0, stream>>>(r32, c32, dinv, h, h1);
    k_biasrelu<<<(NN * EH + 255) / 256, blk, 0, stream>>>(h1, bg);
    k_ab<<<(NN * 64 + 255) / 256, blk, 0, stream>>>(h1, W1, A, B);
    k_cn<<<1, 64, 0, stream>>>(h1, W1, b1, nid, cn);
    k_edge<<<((size_t)NE * 16 + 255) / 256, blk, 0, stream>>>(r32, c32, A, B, cn, W2, b2, eps, out);
}

// Round 2
// 508.181 us; speedup vs baseline: 3.8464x; 3.8464x over previous
//
#include <hip/hip_runtime.h>
#include <math.h>

#define NN 50000
#define NE 1600000
#define FIN 128
#define EH 20
#define DH 64

// ---------------- kernels ----------------

// zero cnt/cursor and detect edge_index element width (int64 vs int32)
__global__ void k_init(int* cnt, int* cursor, int* flag, const void* ei) {
    int i = blockIdx.x * blockDim.x + threadIdx.x;
    if (i < NN) { cnt[i] = 0; cursor[i] = 0; }
    if (blockIdx.x == 0 && threadIdx.x == 0) {
        const int* w = (const int*)ei;
        int all0 = 1;
        for (int j = 1; j < 128; j += 2) all0 &= (w[j] == 0);
        *flag = all0;  // 1 => int64 layout (high words zero), 0 => int32
    }
}

// convert edge_index to int32 r/c arrays and count in-degree of col
__global__ void k_cvt(const void* ei, const int* flag, int* r32, int* c32, int* cnt) {
    int e = blockIdx.x * blockDim.x + threadIdx.x;
    if (e >= NE) return;
    int r, c;
    if (*flag) {
        const long long* p = (const long long*)ei;
        r = (int)p[e];
        c = (int)p[NE + e];
    } else {
        const int* p = (const int*)ei;
        r = p[e];
        c = p[NE + e];
    }
    r32[e] = r;
    c32[e] = c;
    atomicAdd(&cnt[c], 1);
}

// single-block exclusive scan of cnt[NN] -> off[NN+1]
__global__ void k_scan(const int* __restrict__ cnt, int* __restrict__ off) {
    __shared__ int part[1024];
    const int t = threadIdx.x;
    const int CH = (NN + 1023) / 1024;  // 49
    const int base = t * CH;
    int s = 0;
    for (int i = 0; i < CH; ++i) {
        int idx = base + i;
        if (idx < NN) s += cnt[idx];
    }
    part[t] = s;
    __syncthreads();
    for (int d = 1; d < 1024; d <<= 1) {
        int v = 0;
        if (t >= d) v = part[t - d];
        __syncthreads();
        if (t >= d) part[t] += v;
        __syncthreads();
    }
    int excl = (t == 0) ? 0 : part[t - 1];
    for (int i = 0; i < CH; ++i) {
        int idx = base + i;
        if (idx < NN) {
            off[idx] = excl;
            excl += cnt[idx];
        }
    }
    if (t == 1023) off[NN] = excl;  // == NE
}

__global__ void k_dinv(const int* __restrict__ cnt, float* __restrict__ dinv) {
    int i = blockIdx.x * blockDim.x + threadIdx.x;
    if (i < NN) dinv[i] = rsqrtf(1.0f + (float)cnt[i]);  // +1 self loop
}

// hs[n,k] = dinv[n] * dot(x[n,:], W[:,k]) ; 32 threads per node, k = lane (k<20 active)
__global__ void k_xw(const float* __restrict__ x, const float* __restrict__ W,
                     const float* __restrict__ dinv, float* __restrict__ hs) {
    int t = blockIdx.x * blockDim.x + threadIdx.x;
    int n = t >> 5;
    int k = t & 31;
    if (n >= NN || k >= EH) return;
    const float* xr = x + (size_t)n * FIN;
    float acc = 0.f;
#pragma unroll 8
    for (int j = 0; j < FIN; ++j) acc = fmaf(xr[j], W[j * EH + k], acc);
    hs[n * EH + k] = dinv[n] * acc;
}

// bucket-fill CSR: src[off[c] + cursor[c]++] = r
__global__ void k_fill(const int* __restrict__ r32, const int* __restrict__ c32,
                       const int* __restrict__ off, int* __restrict__ cursor,
                       int* __restrict__ src) {
    int e = blockIdx.x * blockDim.x + threadIdx.x;
    if (e >= NE) return;
    int c = c32[e];
    int pos = off[c] + atomicAdd(&cursor[c], 1);
    src[pos] = r32[e];
}

// per-node gather + bias + relu: h1[n,k] = relu(dinv[n]*(hs[n,k] + sum_r hs[r,k]) + b[k])
__global__ void k_gather(const int* __restrict__ off, const int* __restrict__ src,
                         const float* __restrict__ dinv, const float* __restrict__ hs,
                         const float* __restrict__ bg, float* __restrict__ h1) {
    int t = blockIdx.x * blockDim.x + threadIdx.x;
    int n = t >> 5;
    int k = t & 31;
    if (n >= NN || k >= EH) return;
    float acc = hs[n * EH + k];  // self-loop term (already carries dinv[n])
    int e0 = off[n], e1 = off[n + 1];
    for (int e = e0; e < e1; ++e) {
        int r = src[e];
        acc += hs[r * EH + k];
    }
    h1[n * EH + k] = fmaxf(fmaf(dinv[n], acc, bg[k]), 0.f);
}

// A[n,j] = h1[n,:] @ W1[0:20, j];  B[n,j] = h1[n,:] @ W1[20:40, j]
__global__ void k_ab(const float* __restrict__ h1, const float* __restrict__ W1,
                     float* __restrict__ A, float* __restrict__ B) {
    int t = blockIdx.x * blockDim.x + threadIdx.x;
    int n = t >> 6;
    int j = t & 63;
    if (n >= NN) return;
    const float* hr = h1 + (size_t)n * EH;
    float a = 0.f, b = 0.f;
#pragma unroll
    for (int k = 0; k < EH; ++k) {
        float hv = hr[k];
        a = fmaf(hv, W1[k * DH + j], a);
        b = fmaf(hv, W1[(EH + k) * DH + j], b);
    }
    A[(size_t)n * DH + j] = a;
    B[(size_t)n * DH + j] = b;
}

// cn[j] = h1[node_id,:] @ W1[40:60, j] + b1[j]
__global__ void k_cn(const float* __restrict__ h1, const float* __restrict__ W1,
                     const float* __restrict__ b1, const void* nid_p,
                     float* __restrict__ cn) {
    int j = threadIdx.x;  // 64 threads
    int nid = *(const int*)nid_p;  // low 32 bits valid for int32 or int64 LE
    const float* hr = h1 + (size_t)nid * EH;
    float acc = b1[j];
#pragma unroll
    for (int k = 0; k < EH; ++k) acc = fmaf(hr[k], W1[(2 * EH + k) * DH + j], acc);
    cn[j] = acc;
}

// per-edge: out = sigmoid(logit(e) + relu(A[r]+B[c]+cn)@W2 + b2); 16 lanes/edge
__global__ void k_edge(const int* __restrict__ r32, const int* __restrict__ c32,
                       const float* __restrict__ A, const float* __restrict__ B,
                       const float* __restrict__ cn, const float* __restrict__ W2,
                       const float* __restrict__ b2, const float* __restrict__ eps,
                       float* __restrict__ out) {
    int t = blockIdx.x * blockDim.x + threadIdx.x;
    int e = t >> 4;
    if (e >= NE) return;
    int lane = t & 15;
    int r = r32[e], c = c32[e];
    float4 a  = *(const float4*)(A  + (size_t)r * DH + lane * 4);
    float4 bb = *(const float4*)(B  + (size_t)c * DH + lane * 4);
    float4 cc = *(const float4*)(cn + lane * 4);
    float4 w  = *(const float4*)(W2 + lane * 4);
    float p = fmaxf(a.x + bb.x + cc.x, 0.f) * w.x
            + fmaxf(a.y + bb.y + cc.y, 0.f) * w.y
            + fmaxf(a.z + bb.z + cc.z, 0.f) * w.z
            + fmaxf(a.w + bb.w + cc.w, 0.f) * w.w;
    p += __shfl_xor(p, 1);
    p += __shfl_xor(p, 2);
    p += __shfl_xor(p, 4);
    p += __shfl_xor(p, 8);
    if (lane == 0) {
        float ep = eps[e];
        // e = (bias-(1-bias))*eps + (1-bias), bias=1e-4
        float ee = fmaf(-0.9998f, ep, 0.9999f);
        float gate = logf(ee) - log1pf(-ee) + p + b2[0];
        out[e] = 1.0f / (1.0f + expf(-gate));
    }
}

// ---------------- launch ----------------

extern "C" void kernel_launch(void* const* d_in, const int* in_sizes, int n_in,
                              void* d_out, int out_size, void* d_ws, size_t ws_size,
                              hipStream_t stream) {
    const float* x   = (const float*)d_in[0];
    const void*  ei  = d_in[1];
    const void*  nid = d_in[2];
    const float* eps = (const float*)d_in[3];
    const float* Wg  = (const float*)d_in[4];
    const float* bg  = (const float*)d_in[5];
    const float* W1  = (const float*)d_in[6];
    const float* b1  = (const float*)d_in[7];
    const float* W2  = (const float*)d_in[8];
    const float* b2  = (const float*)d_in[9];
    float* out = (float*)d_out;

    float* ws = (float*)d_ws;
    // A (3.2M) at 0; src (1.6M, dead before k_ab) aliases A's front.
    // B (3.2M) at 3.2M; scan temporaries (dead before k_ab) alias B.
    float* A    = ws + 0;
    int*   src  = (int*)(ws + 0);
    float* B    = ws + 3200000;
    int*   cnt    = (int*)(ws + 3200000);
    int*   cursor = (int*)(ws + 3264000);
    int*   off    = (int*)(ws + 3328000);
    float* dinv   = ws + 3392000;
    int*   flag   = (int*)(ws + 3456000);
    float* h1   = ws + 6400000;
    float* hs   = ws + 7400000;
    int*   r32  = (int*)(ws + 8400000);
    int*   c32  = (int*)(ws + 10000000);
    float* cn   = ws + 11600000;

    dim3 blk(256);
    k_init<<<(NN + 255) / 256, blk, 0, stream>>>(cnt, cursor, flag, ei);
    k_cvt<<<(NE + 255) / 256, blk, 0, stream>>>(ei, flag, r32, c32, cnt);
    k_scan<<<1, 1024, 0, stream>>>(cnt, off);
    k_dinv<<<(NN + 255) / 256, blk, 0, stream>>>(cnt, dinv);
    k_xw<<<(NN * 32 + 255) / 256, blk, 0, stream>>>(x, Wg, dinv, hs);
    k_fill<<<(NE + 255) / 256, blk, 0, stream>>>(r32, c32, off, cursor, src);
    k_gather<<<(NN * 32 + 255) / 256, blk, 0, stream>>>(off, src, dinv, hs, bg, h1);
    k_ab<<<(NN * 64 + 255) / 256, blk, 0, stream>>>(h1, W1, A, B);
    k_cn<<<1, 64, 0, stream>>>(h1, W1, b1, nid, cn);
    k_edge<<<((size_t)NE * 16 + 255) / 256, blk, 0, stream>>>(r32, c32, A, B, cn, W2, b2, eps, out);
}